// Round 2
// baseline (804.698 us; speedup 1.0000x reference)
//
#include <hip/hip_runtime.h>

// Problem constants
#define BS    8
#define CDIM  4096
#define TDIM  512
#define NH    8
#define HD    64
#define NDIM  512          // H*HD == OUT_DIM == T
#define MROWS (BS * CDIM)  // 32768
// SCALE = sqrt(512)
#define INV_SCALE 0.044194173824159216f

typedef __bf16 bf16x8 __attribute__((ext_vector_type(8)));
typedef float  f32x4  __attribute__((ext_vector_type(4)));

static __device__ __forceinline__ float b2f(unsigned short u) {
    union { unsigned int i; float f; } x; x.i = ((unsigned int)u) << 16; return x.f;
}
static __device__ __forceinline__ unsigned short f2b(float f) {
    union { float f; unsigned int i; } x; x.f = f;
    unsigned int r = x.i + 0x7FFFu + ((x.i >> 16) & 1u);   // RNE
    return (unsigned short)(r >> 16);
}

// ---------------------------------------------------------------------------
// Input-dtype detector. If the buffer holds fp32, even-index ushorts are the
// LOW mantissa halves (uniform random bits) -> ~25% have bf16-exponent-field
// >= 0xC0 (|x| >= 2^65). Genuine bf16 N(0,1) data: ~0%. flag=1 -> fp32.
// ---------------------------------------------------------------------------
__global__ __launch_bounds__(256) void detect_kernel(
    const unsigned short* __restrict__ q, int* __restrict__ flag)
{
    __shared__ int cnt_s;
    if (threadIdx.x == 0) cnt_s = 0;
    __syncthreads();
    int c = 0;
    for (int i = threadIdx.x; i < 8192; i += 256) {
        unsigned short u = q[2 * i];
        int e = (u >> 7) & 0xFF;
        if (e >= 0xC0) c++;
    }
    atomicAdd(&cnt_s, c);
    __syncthreads();
    if (threadIdx.x == 0) flag[0] = (cnt_s > 256) ? 1 : 0;
}

// ---------------------------------------------------------------------------
// C[M][N] = A[M][K] * B[N][K]^T ; fp32 accum, bf16 MFMA.
// a_dyn/b_dyn: operand dtype follows flag (1=fp32 when flag set) else bf16.
// c_dyn: output written fp32 when flag set, else bf16.
// M % 64 == 0, N % 64 == 0, K % 32 == 0.
// ---------------------------------------------------------------------------
__global__ __launch_bounds__(256) void gemm_bt_kernel(
    const void* __restrict__ Av, const void* __restrict__ Bv,
    void* __restrict__ Cv, int M, int N, int K,
    const int* __restrict__ flag, int a_dyn, int b_dyn, int c_dyn)
{
    constexpr int TM = 64, TN = 64, TK = 32, PAD = 8;
    __shared__ unsigned short As[TM][TK + PAD];   // row stride 80B -> 2-way max
    __shared__ unsigned short Bs[TN][TK + PAD];

    const int f = *flag;
    const bool a32 = (a_dyn != 0) && (f != 0);
    const bool b32 = (b_dyn != 0) && (f != 0);
    const bool c32 = (c_dyn != 0) && (f != 0);

    const int tid  = threadIdx.x;
    const int wave = tid >> 6;
    const int lane = tid & 63;
    const int quad = lane >> 4;
    const int l16  = lane & 15;
    const int m0 = blockIdx.x * TM;
    const int n0 = blockIdx.y * TN;

    f32x4 acc[4];
#pragma unroll
    for (int i = 0; i < 4; i++) acc[i] = (f32x4){0.f, 0.f, 0.f, 0.f};

    const int ldrow = tid >> 2;        // 0..63
    const int ldseg = (tid & 3) * 8;   // 0,8,16,24

    for (int k0 = 0; k0 < K; k0 += TK) {
        __syncthreads();
        {
            alignas(16) unsigned short t8[8];
            if (a32) {
                const float* A = (const float*)Av;
                const float* p = &A[(size_t)(m0 + ldrow) * K + k0 + ldseg];
                float4 lo = *(const float4*)p;
                float4 hi = *(const float4*)(p + 4);
                t8[0] = f2b(lo.x); t8[1] = f2b(lo.y); t8[2] = f2b(lo.z); t8[3] = f2b(lo.w);
                t8[4] = f2b(hi.x); t8[5] = f2b(hi.y); t8[6] = f2b(hi.z); t8[7] = f2b(hi.w);
                *(float4*)&As[ldrow][ldseg] = *(const float4*)t8;
            } else {
                const unsigned short* A = (const unsigned short*)Av;
                *(float4*)&As[ldrow][ldseg] =
                    *(const float4*)&A[(size_t)(m0 + ldrow) * K + k0 + ldseg];
            }
            if (b32) {
                const float* B = (const float*)Bv;
                const float* p = &B[(size_t)(n0 + ldrow) * K + k0 + ldseg];
                float4 lo = *(const float4*)p;
                float4 hi = *(const float4*)(p + 4);
                t8[0] = f2b(lo.x); t8[1] = f2b(lo.y); t8[2] = f2b(lo.z); t8[3] = f2b(lo.w);
                t8[4] = f2b(hi.x); t8[5] = f2b(hi.y); t8[6] = f2b(hi.z); t8[7] = f2b(hi.w);
                *(float4*)&Bs[ldrow][ldseg] = *(const float4*)t8;
            } else {
                const unsigned short* B = (const unsigned short*)Bv;
                *(float4*)&Bs[ldrow][ldseg] =
                    *(const float4*)&B[(size_t)(n0 + ldrow) * K + k0 + ldseg];
            }
        }
        __syncthreads();

        // A fragment: A[m = lane&15][k = quad*8 + j]  (m89-verified layout)
        bf16x8 a = *(const bf16x8*)&As[wave * 16 + l16][quad * 8];
#pragma unroll
        for (int nb = 0; nb < 4; nb++) {
            bf16x8 b = *(const bf16x8*)&Bs[nb * 16 + l16][quad * 8];
            acc[nb] = __builtin_amdgcn_mfma_f32_16x16x32_bf16(a, b, acc[nb], 0, 0, 0);
        }
    }

    // C/D layout: col = lane&15, row = quad*4 + reg   (m89-verified)
#pragma unroll
    for (int nb = 0; nb < 4; nb++) {
#pragma unroll
        for (int r = 0; r < 4; r++) {
            int row = m0 + wave * 16 + quad * 4 + r;
            int col = n0 + nb * 16 + l16;
            if (c32) ((float*)Cv)[(size_t)row * N + col] = acc[nb][r];
            else ((unsigned short*)Cv)[(size_t)row * N + col] = f2b(acc[nb][r]);
        }
    }
}

// ---------------------------------------------------------------------------
// scores[bh][d][e] += sum_{c in chunk} qh[b,c,h,d] * kh[b,c,h,e]
// grid (64, NCHUNK), block 256. fp32 atomic accumulate (scores pre-zeroed).
// ---------------------------------------------------------------------------
#define NCHUNK 16
#define CPC (CDIM / NCHUNK)   // 256

__global__ __launch_bounds__(256) void scores_kernel(
    const unsigned short* __restrict__ qh,
    const unsigned short* __restrict__ kh,
    float* __restrict__ scores)
{
    const int bh = blockIdx.x;
    const int b = bh >> 3, h = bh & 7;
    const int c0 = blockIdx.y * CPC;
    const int t = threadIdx.x;

    __shared__ float qs[8][64];
    __shared__ float ks[8][64];

    const int dd = t >> 2;          // d row: 0..63
    const int e0 = (t & 3) * 16;    // e span of 16

    float acc[16];
#pragma unroll
    for (int i = 0; i < 16; i++) acc[i] = 0.f;

    const size_t base = ((size_t)b * CDIM + c0) * NDIM + h * HD;

    for (int cc = 0; cc < CPC; cc += 8) {
        __syncthreads();
        for (int i = t; i < 512; i += 256) {
            int cl = i >> 6, d = i & 63;
            size_t g = base + (size_t)(cc + cl) * NDIM + d;
            qs[cl][d] = b2f(qh[g]);
            ks[cl][d] = b2f(kh[g]);
        }
        __syncthreads();
#pragma unroll
        for (int j = 0; j < 8; j++) {
            float qv = qs[j][dd];
#pragma unroll
            for (int i = 0; i < 16; i++) acc[i] += qv * ks[j][e0 + i];
        }
    }

    float* sb = scores + (size_t)bh * (HD * HD) + dd * HD + e0;
#pragma unroll
    for (int i = 0; i < 16; i++) atomicAdd(&sb[i], acc[i]);
}

// ---------------------------------------------------------------------------
// softmax over e (64) of scores[bh][d][e] * (1/SCALE) -> w (fp32)
// grid 64 (bh), block 64 (lane = d)
// ---------------------------------------------------------------------------
__global__ __launch_bounds__(64) void softmax_kernel(
    const float* __restrict__ scores, float* __restrict__ w)
{
    const int bh = blockIdx.x;
    const int d  = threadIdx.x;
    const float* s = scores + (size_t)bh * (HD * HD) + d * HD;
    float v[64];
    float m = -1e30f;
#pragma unroll
    for (int e = 0; e < 64; e++) { v[e] = s[e] * INV_SCALE; m = fmaxf(m, v[e]); }
    float sum = 0.f;
#pragma unroll
    for (int e = 0; e < 64; e++) { v[e] = __expf(v[e] - m); sum += v[e]; }
    float r = 1.0f / sum;
    float* o = w + (size_t)bh * (HD * HD) + d * HD;
#pragma unroll
    for (int e = 0; e < 64; e++) o[e] = v[e] * r;
}

// ---------------------------------------------------------------------------
// cat[b,c,h*64+d] = sum_e w[bh][d][e] * vh[b,c,h,e]
// grid (64, 64) = (bh, c-block of 64), block 256
// ---------------------------------------------------------------------------
__global__ __launch_bounds__(256) void attn_kernel(
    const float* __restrict__ w,
    const unsigned short* __restrict__ vh,
    unsigned short* __restrict__ cat)
{
    const int bh = blockIdx.x;
    const int b = bh >> 3, h = bh & 7;
    const int c0 = blockIdx.y * 64;
    const int t = threadIdx.x;

    __shared__ float ws[64][65];   // +1 pad: <=2-way conflicts (free)
    __shared__ float vs[64][65];

    for (int i = t; i < 4096; i += 256) ws[i >> 6][i & 63] = w[(size_t)bh * 4096 + i];
    const size_t vb = ((size_t)b * CDIM + c0) * NDIM + h * HD;
    for (int i = t; i < 4096; i += 256) {
        int cl = i >> 6, e = i & 63;
        vs[cl][e] = b2f(vh[vb + (size_t)cl * NDIM + e]);
    }
    __syncthreads();

    const int cl = t >> 2;
    const int d0 = (t & 3) * 16;
    float acc[16];
#pragma unroll
    for (int i = 0; i < 16; i++) acc[i] = 0.f;

    for (int e = 0; e < 64; e++) {
        float v = vs[cl][e];
#pragma unroll
        for (int i = 0; i < 16; i++) acc[i] += v * ws[d0 + i][e];
    }

    unsigned short* o = cat + ((size_t)(b * CDIM + c0 + cl)) * NDIM + h * HD + d0;
#pragma unroll
    for (int i = 0; i < 16; i++) o[i] = f2b(acc[i]);
}

// ---------------------------------------------------------------------------
extern "C" void kernel_launch(void* const* d_in, const int* in_sizes, int n_in,
                              void* d_out, int out_size, void* d_ws, size_t ws_size,
                              hipStream_t stream)
{
    const void* q  = d_in[0];
    const void* k  = d_in[1];
    const void* v  = d_in[2];
    const void* Wq = d_in[3];
    const void* Wk = d_in[4];
    const void* Wv = d_in[5];
    const void* Wo = d_in[6];

    const size_t MAT = (size_t)MROWS * NDIM;   // 16,777,216 elements
    unsigned short* qh  = (unsigned short*)d_ws;      // bf16, 32 MB
    unsigned short* kh  = qh + MAT;
    unsigned short* vh  = kh + MAT;
    float* scores = (float*)(vh + MAT);               // 1 MB fp32
    float* wsm    = scores + 64 * 64 * 64;            // 1 MB fp32
    unsigned short* cat = qh;  // qh dead after scores_kernel -> alias
    int* flag = (int*)(wsm + 64 * 64 * 64);

    detect_kernel<<<1, 256, 0, stream>>>((const unsigned short*)q, flag);
    hipMemsetAsync(scores, 0, 64 * 64 * 64 * sizeof(float), stream);

    dim3 gg(MROWS / 64, NDIM / 64);  // (512, 8)
    // projections: A = q/k/v (dyn), B = W (dyn), C = bf16 intermediate
    gemm_bt_kernel<<<gg, 256, 0, stream>>>(q, Wq, qh, MROWS, NDIM, TDIM, flag, 1, 1, 0);
    gemm_bt_kernel<<<gg, 256, 0, stream>>>(k, Wk, kh, MROWS, NDIM, TDIM, flag, 1, 1, 0);
    gemm_bt_kernel<<<gg, 256, 0, stream>>>(v, Wv, vh, MROWS, NDIM, TDIM, flag, 1, 1, 0);

    scores_kernel<<<dim3(64, NCHUNK), 256, 0, stream>>>(qh, kh, scores);
    softmax_kernel<<<64, 64, 0, stream>>>(scores, wsm);
    attn_kernel<<<dim3(64, CDIM / 64), 256, 0, stream>>>(wsm, vh, cat);

    // final: A = cat (bf16), B = Wo (dyn), C = d_out (follows flag)
    gemm_bt_kernel<<<gg, 256, 0, stream>>>(cat, Wo, d_out, MROWS, NDIM, TDIM, flag, 0, 1, 1);
}

// Round 3
// 483.473 us; speedup vs baseline: 1.6644x; 1.6644x over previous
//
#include <hip/hip_runtime.h>

// Problem constants (all fp32 in global memory — verified round 2)
#define BS    8
#define CDIM  4096
#define TDIM  512
#define NH    8
#define HD    64
#define NDIM  512
#define INV_SCALE 0.044194173824159216f   // 1/sqrt(512)

typedef __bf16 bf16x8 __attribute__((ext_vector_type(8)));
typedef float  f32x4  __attribute__((ext_vector_type(4)));

static __device__ __forceinline__ float b2f(unsigned short u) {
    union { unsigned int i; float f; } x; x.i = ((unsigned int)u) << 16; return x.f;
}
static __device__ __forceinline__ unsigned short f2b(float f) {
    union { float f; unsigned int i; } x; x.f = f;
    unsigned int r = x.i + 0x7FFFu + ((x.i >> 16) & 1u);   // RNE
    return (unsigned short)(r >> 16);
}

// ---------------------------------------------------------------------------
// G[b][t][s] = sum_c q[b][c][t] * k[b][c][s]   (contraction over ROWS)
// q,k fp32 (C x T row-major per batch); G bf16 (512x512 per batch).
// Tile 64x64, TK=32 over c; LDS-transposed staging (rows become k-contiguous).
// grid (8, 8, BS), block 256.
// ---------------------------------------------------------------------------
__global__ __launch_bounds__(256) void gemm_atb_kernel(
    const float* __restrict__ q, const float* __restrict__ k,
    unsigned short* __restrict__ G)
{
    constexpr int RL = 40;                    // LDS row len (shorts), 80B rows
    __shared__ unsigned short As[64][RL];     // [t][c]
    __shared__ unsigned short Bs[64][RL];     // [s][c]

    const int tid  = threadIdx.x;
    const int wave = tid >> 6;
    const int lane = tid & 63;
    const int quad = lane >> 4;
    const int l16  = lane & 15;
    const int t0 = blockIdx.x * 64;
    const int s0 = blockIdx.y * 64;
    const int b  = blockIdx.z;

    const float* A = q + (size_t)b * CDIM * TDIM;
    const float* B = k + (size_t)b * CDIM * TDIM;

    f32x4 acc[4];
#pragma unroll
    for (int i = 0; i < 4; i++) acc[i] = (f32x4){0.f, 0.f, 0.f, 0.f};

    const int c_l = tid & 31;       // c within chunk
    const int tf  = tid >> 5;       // 0..7 -> 8-float t segment

    for (int c0 = 0; c0 < CDIM; c0 += 32) {
        __syncthreads();
        {
            const float* pA = A + (size_t)(c0 + c_l) * TDIM + t0 + tf * 8;
            const float* pB = B + (size_t)(c0 + c_l) * TDIM + s0 + tf * 8;
            float4 a0 = *(const float4*)pA, a1 = *(const float4*)(pA + 4);
            float4 b0 = *(const float4*)pB, b1 = *(const float4*)(pB + 4);
            As[tf * 8 + 0][c_l] = f2b(a0.x); As[tf * 8 + 1][c_l] = f2b(a0.y);
            As[tf * 8 + 2][c_l] = f2b(a0.z); As[tf * 8 + 3][c_l] = f2b(a0.w);
            As[tf * 8 + 4][c_l] = f2b(a1.x); As[tf * 8 + 5][c_l] = f2b(a1.y);
            As[tf * 8 + 6][c_l] = f2b(a1.z); As[tf * 8 + 7][c_l] = f2b(a1.w);
            Bs[tf * 8 + 0][c_l] = f2b(b0.x); Bs[tf * 8 + 1][c_l] = f2b(b0.y);
            Bs[tf * 8 + 2][c_l] = f2b(b0.z); Bs[tf * 8 + 3][c_l] = f2b(b0.w);
            Bs[tf * 8 + 4][c_l] = f2b(b1.x); Bs[tf * 8 + 5][c_l] = f2b(b1.y);
            Bs[tf * 8 + 6][c_l] = f2b(b1.z); Bs[tf * 8 + 7][c_l] = f2b(b1.w);
        }
        __syncthreads();

        bf16x8 a = *(const bf16x8*)&As[wave * 16 + l16][quad * 8];
#pragma unroll
        for (int nb = 0; nb < 4; nb++) {
            bf16x8 bb = *(const bf16x8*)&Bs[nb * 16 + l16][quad * 8];
            acc[nb] = __builtin_amdgcn_mfma_f32_16x16x32_bf16(a, bb, acc[nb], 0, 0, 0);
        }
    }

    unsigned short* Cb = G + (size_t)b * TDIM * TDIM;
#pragma unroll
    for (int nb = 0; nb < 4; nb++) {
#pragma unroll
        for (int r = 0; r < 4; r++) {
            int row = t0 + wave * 16 + quad * 4 + r;
            int col = s0 + nb * 16 + l16;
            Cb[(size_t)row * TDIM + col] = f2b(acc[nb][r]);
        }
    }
}

// ---------------------------------------------------------------------------
// Generic batched C[m][n] = sum_k A[m][k] * B[n][k]  (both k-contiguous).
// Per blockIdx.z: b = bz>>hshift, h = bz&hmask; operand offsets = b*s?b + h*s?h.
// a_f32/b_f32: operand dtype. c_f32: C dtype. writeT: store C[n*ldc+m].
// M%64==0, N%64==0, K%32==0.
// ---------------------------------------------------------------------------
__global__ __launch_bounds__(256) void gemm_bt_kernel(
    const void* __restrict__ Av, int a_f32, size_t sAb, size_t sAh,
    const void* __restrict__ Bv, int b_f32, size_t sBb, size_t sBh,
    void* __restrict__ Cv, int c_f32, int writeT, int ldc, size_t sCb, size_t sCh,
    int M, int N, int K, int hshift, int hmask)
{
    constexpr int PAD = 8;
    __shared__ unsigned short As[64][32 + PAD];
    __shared__ unsigned short Bs[64][32 + PAD];

    const int tid  = threadIdx.x;
    const int wave = tid >> 6;
    const int lane = tid & 63;
    const int quad = lane >> 4;
    const int l16  = lane & 15;
    const int m0 = blockIdx.x * 64;
    const int n0 = blockIdx.y * 64;
    const int bz = blockIdx.z;
    const int b = bz >> hshift, h = bz & hmask;

    f32x4 acc[4];
#pragma unroll
    for (int i = 0; i < 4; i++) acc[i] = (f32x4){0.f, 0.f, 0.f, 0.f};

    const int ldrow = tid >> 2;        // 0..63
    const int ldseg = (tid & 3) * 8;   // 0,8,16,24

    const size_t offA = (size_t)b * sAb + (size_t)h * sAh;
    const size_t offB = (size_t)b * sBb + (size_t)h * sBh;

    for (int k0 = 0; k0 < K; k0 += 32) {
        __syncthreads();
        if (a_f32) {
            const float* p = (const float*)Av + offA + (size_t)(m0 + ldrow) * K + k0 + ldseg;
            float4 lo = *(const float4*)p, hi = *(const float4*)(p + 4);
            alignas(16) unsigned short t8[8] = {
                f2b(lo.x), f2b(lo.y), f2b(lo.z), f2b(lo.w),
                f2b(hi.x), f2b(hi.y), f2b(hi.z), f2b(hi.w)};
            *(float4*)&As[ldrow][ldseg] = *(const float4*)t8;
        } else {
            const unsigned short* p = (const unsigned short*)Av + offA +
                                      (size_t)(m0 + ldrow) * K + k0 + ldseg;
            *(float4*)&As[ldrow][ldseg] = *(const float4*)p;
        }
        if (b_f32) {
            const float* p = (const float*)Bv + offB + (size_t)(n0 + ldrow) * K + k0 + ldseg;
            float4 lo = *(const float4*)p, hi = *(const float4*)(p + 4);
            alignas(16) unsigned short t8[8] = {
                f2b(lo.x), f2b(lo.y), f2b(lo.z), f2b(lo.w),
                f2b(hi.x), f2b(hi.y), f2b(hi.z), f2b(hi.w)};
            *(float4*)&Bs[ldrow][ldseg] = *(const float4*)t8;
        } else {
            const unsigned short* p = (const unsigned short*)Bv + offB +
                                      (size_t)(n0 + ldrow) * K + k0 + ldseg;
            *(float4*)&Bs[ldrow][ldseg] = *(const float4*)p;
        }
        __syncthreads();

        bf16x8 a = *(const bf16x8*)&As[wave * 16 + l16][quad * 8];
#pragma unroll
        for (int nb = 0; nb < 4; nb++) {
            bf16x8 bb = *(const bf16x8*)&Bs[nb * 16 + l16][quad * 8];
            acc[nb] = __builtin_amdgcn_mfma_f32_16x16x32_bf16(a, bb, acc[nb], 0, 0, 0);
        }
    }

    const size_t offC = (size_t)b * sCb + (size_t)h * sCh;
#pragma unroll
    for (int nb = 0; nb < 4; nb++) {
#pragma unroll
        for (int r = 0; r < 4; r++) {
            int row = m0 + wave * 16 + quad * 4 + r;   // m
            int col = n0 + nb * 16 + l16;              // n
            size_t idx = offC + (writeT ? (size_t)col * ldc + row
                                        : (size_t)row * ldc + col);
            if (c_f32) ((float*)Cv)[idx] = acc[nb][r];
            else ((unsigned short*)Cv)[idx] = f2b(acc[nb][r]);
        }
    }
}

// ---------------------------------------------------------------------------
// WvT[h][t][e] = bf16(Wv[h][e][t])  (8 x 64 x 512 fp32 -> 8 x 512 x 64 bf16)
// ---------------------------------------------------------------------------
__global__ __launch_bounds__(256) void transpose_wv_kernel(
    const float* __restrict__ Wv, unsigned short* __restrict__ WvT)
{
    int i = blockIdx.x * 256 + threadIdx.x;            // 262144 total
    int h = i >> 15, r = i & 32767;
    int t = r >> 6, e = i & 63;
    WvT[i] = f2b(Wv[(size_t)h * 32768 + (size_t)e * 512 + t]);
}

// ---------------------------------------------------------------------------
// softmax over e of S[bh][d][e]*INV_SCALE -> w bf16
// grid 64 (bh), block 64 (d)
// ---------------------------------------------------------------------------
__global__ __launch_bounds__(64) void softmax_kernel(
    const float* __restrict__ S, unsigned short* __restrict__ w)
{
    const int bh = blockIdx.x;
    const int d  = threadIdx.x;
    const float* s = S + (size_t)bh * (HD * HD) + d * HD;
    float v[64];
    float m = -1e30f;
#pragma unroll
    for (int e = 0; e < 64; e++) { v[e] = s[e] * INV_SCALE; m = fmaxf(m, v[e]); }
    float sum = 0.f;
#pragma unroll
    for (int e = 0; e < 64; e++) { v[e] = __expf(v[e] - m); sum += v[e]; }
    float rinv = 1.0f / sum;
    unsigned short* o = w + (size_t)bh * (HD * HD) + d * HD;
#pragma unroll
    for (int e = 0; e < 64; e++) o[e] = f2b(v[e] * rinv);
}

// ---------------------------------------------------------------------------
extern "C" void kernel_launch(void* const* d_in, const int* in_sizes, int n_in,
                              void* d_out, int out_size, void* d_ws, size_t ws_size,
                              hipStream_t stream)
{
    const float* q  = (const float*)d_in[0];
    const float* k  = (const float*)d_in[1];
    const float* v  = (const float*)d_in[2];
    const float* Wq = (const float*)d_in[3];
    const float* Wk = (const float*)d_in[4];
    const float* Wv = (const float*)d_in[5];
    const float* Wo = (const float*)d_in[6];

    // workspace layout (shorts unless noted)
    unsigned short* G    = (unsigned short*)d_ws;      // 8*512*512       (4 MB)
    unsigned short* tmpT = G + 2097152;                // 64*64*512       (4 MB)
    float*          S    = (float*)(tmpT + 2097152);   // 64*64*64 fp32   (1 MB)
    unsigned short* w    = (unsigned short*)(S + 262144); // 64*64*64     (.5 MB)
    unsigned short* WvT  = w + 262144;                 // 8*512*64        (.5 MB)
    unsigned short* WveT = WvT + 262144;               // 8*512*512       (4 MB)
    unsigned short* W2   = WveT + 2097152;             // 8*512*512       (4 MB)

    // 1. G[b] = q[b]^T k[b]   (17.2 GF)
    gemm_atb_kernel<<<dim3(8, 8, BS), 256, 0, stream>>>(q, k, G);

    // (prep) WvT
    transpose_wv_kernel<<<1024, 256, 0, stream>>>(Wv, WvT);

    // 2a. tmpT[b,h][e][t] = (G[b] * Wk[h]^T)^T   M=512(t) N=64(e) K=512(s)
    gemm_bt_kernel<<<dim3(8, 1, 64), 256, 0, stream>>>(
        G, 0, 262144, 0, Wk, 1, 0, 32768,
        tmpT, 0, 1, 512, 262144, 32768, 512, 64, 512, 3, 7);

    // 2b. S[b,h][d][e] = Wq[h] * tmpT[b,h]^T     M=64(d) N=64(e) K=512(t)
    gemm_bt_kernel<<<dim3(1, 1, 64), 256, 0, stream>>>(
        Wq, 1, 0, 32768, tmpT, 0, 262144, 32768,
        S, 1, 0, 64, 32768, 4096, 64, 64, 512, 3, 7);

    // 3. softmax -> w bf16
    softmax_kernel<<<64, 64, 0, stream>>>(S, w);

    // 4. WveT[b][t][h*64+d] = (w[b,h] * WvT[h]^T)^T   M=64(d) N=512(t) K=64(e)
    gemm_bt_kernel<<<dim3(1, 8, 64), 256, 0, stream>>>(
        w, 0, 32768, 4096, WvT, 0, 0, 32768,
        WveT, 0, 1, 512, 262144, 64, 64, 512, 64, 3, 7);

    // 5. W2[b][o][t] = Wo * WveT[b]^T             M=512(o) N=512(t) K=512(n)
    gemm_bt_kernel<<<dim3(8, 8, BS), 256, 0, stream>>>(
        Wo, 1, 0, 0, WveT, 0, 262144, 0,
        W2, 0, 0, 512, 262144, 0, 512, 512, 512, 0, 0);

    // 6. out[b] = v[b] * W2[b]^T                  M=4096(c) N=512(o) K=512(t)
    gemm_bt_kernel<<<dim3(64, 8, BS), 256, 0, stream>>>(
        v, 1, 2097152, 0, W2, 0, 262144, 0,
        d_out, 1, 0, 512, 2097152, 0, CDIM, 512, 512, 0, 0);
}

// Round 4
// 416.218 us; speedup vs baseline: 1.9334x; 1.1616x over previous
//
#include <hip/hip_runtime.h>

// Problem constants (all fp32 in global memory — verified round 2)
#define BS    8
#define CDIM  4096
#define TDIM  512
#define NH    8
#define HD    64
#define NDIM  512
#define INV_SCALE 0.044194173824159216f   // 1/sqrt(512)

typedef __bf16 bf16x8 __attribute__((ext_vector_type(8)));
typedef float  f32x4  __attribute__((ext_vector_type(4)));

static __device__ __forceinline__ unsigned short f2b(float f) {
    union { float f; unsigned int i; } x; x.f = f;
    unsigned int r = x.i + 0x7FFFu + ((x.i >> 16) & 1u);   // RNE
    return (unsigned short)(r >> 16);
}

static __device__ __forceinline__ void gl2lds16(const unsigned short* g,
                                                unsigned short* l) {
    __builtin_amdgcn_global_load_lds(
        (const __attribute__((address_space(1))) void*)g,
        (__attribute__((address_space(3))) void*)l, 16, 0, 0);
}

// ---------------------------------------------------------------------------
// Transpose+convert: x[b][c][t] fp32 -> xT[b][t][c] bf16.  64x64 tiles.
// grid (CDIM/64, TDIM/64, 16): z>>3 selects q/k, b = z&7. block 256.
// LDS stride 65 shorts -> both scalar phases conflict-free (addr%64 unique).
// ---------------------------------------------------------------------------
__global__ __launch_bounds__(256) void transpose_qk_kernel(
    const float* __restrict__ q, const float* __restrict__ k,
    unsigned short* __restrict__ qT, unsigned short* __restrict__ kT)
{
    __shared__ unsigned short Ls[64 * 65];

    const int z = blockIdx.z;
    const int b = z & 7;
    const float* src = (z >> 3) ? k : q;
    unsigned short* dst = (z >> 3) ? kT : qT;

    const int c0 = blockIdx.x * 64;
    const int t0 = blockIdx.y * 64;
    const int tid = threadIdx.x;

    // load: row r (c-local) = tid>>2, 16 floats at t-seg (tid&3)*16
    {
        const int r = tid >> 2, seg = (tid & 3) * 16;
        const float* p = src + ((size_t)b * CDIM + c0 + r) * TDIM + t0 + seg;
        float4 f0 = *(const float4*)p, f1 = *(const float4*)(p + 4);
        float4 f2 = *(const float4*)(p + 8), f3 = *(const float4*)(p + 12);
        float ff[16] = {f0.x, f0.y, f0.z, f0.w, f1.x, f1.y, f1.z, f1.w,
                        f2.x, f2.y, f2.z, f2.w, f3.x, f3.y, f3.z, f3.w};
#pragma unroll
        for (int j = 0; j < 16; j++) Ls[(seg + j) * 65 + r] = f2b(ff[j]);
    }
    __syncthreads();
    // store: row t' = tid>>2, 16 shorts at c-seg (tid&3)*16
    {
        const int tp = tid >> 2, cs = (tid & 3) * 16;
        alignas(16) unsigned short u[16];
#pragma unroll
        for (int j = 0; j < 16; j++) u[j] = Ls[tp * 65 + cs + j];
        unsigned short* o = dst + ((size_t)b * TDIM + t0 + tp) * CDIM + c0 + cs;
        *(float4*)o = *(const float4*)u;
        *(float4*)(o + 8) = *(const float4*)(u + 8);
    }
}

// ---------------------------------------------------------------------------
// Elementwise fp32 -> bf16 (n must be multiple of 8; one thread = 8 elems)
// ---------------------------------------------------------------------------
__global__ __launch_bounds__(256) void cvt_kernel(
    const float* __restrict__ in, unsigned short* __restrict__ out, int n8)
{
    int i = blockIdx.x * 256 + threadIdx.x;
    if (i >= n8) return;
    float4 f0 = ((const float4*)in)[i * 2], f1 = ((const float4*)in)[i * 2 + 1];
    alignas(16) unsigned short t[8] = {f2b(f0.x), f2b(f0.y), f2b(f0.z), f2b(f0.w),
                                       f2b(f1.x), f2b(f1.y), f2b(f1.z), f2b(f1.w)};
    ((float4*)out)[i] = *(const float4*)t;
}

// ---------------------------------------------------------------------------
// m97-style 128x128 GEMM: C[m][n] = sum_k A[m][k] * B[n][k].
// B always bf16 via global_load_lds(16B). A: bf16 DMA path, or fp32
// VGPR-staged (a_f32, block-uniform). ldk = row stride of A and B.
// grid (M/128, N/128, batches). Tiles: BK=32, 4 waves -> 64x64 quadrant each.
// ---------------------------------------------------------------------------
__global__ __launch_bounds__(256) void gemm128_kernel(
    const void* __restrict__ Av, int a_f32, size_t sAb,
    const unsigned short* __restrict__ B, size_t sBb,
    void* __restrict__ Cv, int c_f32, int writeT, int ldc, size_t sCb,
    int ldk, int K)
{
    __shared__ unsigned short As[128 * 32];
    __shared__ unsigned short Bs[128 * 32];

    const int tid  = threadIdx.x;
    const int wave = tid >> 6, lane = tid & 63;
    const int quad = lane >> 4, l16 = lane & 15;
    const int wm = wave >> 1, wn = wave & 1;
    const int m0 = blockIdx.x * 128, n0 = blockIdx.y * 128;
    const int b = blockIdx.z;

    const unsigned short* Bb = B + (size_t)b * sBb;

    f32x4 acc[4][4];
#pragma unroll
    for (int i = 0; i < 4; i++)
#pragma unroll
        for (int j = 0; j < 4; j++) acc[i][j] = (f32x4){0.f, 0.f, 0.f, 0.f};

    const int ldr = lane >> 2, ldc8 = (lane & 3) * 8;  // DMA row/col within panel
    const int ar = tid >> 1, as0 = (tid & 1) * 16;     // fp32-stage row/seg

    for (int k0 = 0; k0 < K; k0 += 32) {
        __syncthreads();
        if (a_f32) {
            const float* Ab = (const float*)Av + (size_t)b * sAb +
                              (size_t)(m0 + ar) * ldk + k0 + as0;
            float4 f0 = *(const float4*)Ab,       f1 = *(const float4*)(Ab + 4);
            float4 f2 = *(const float4*)(Ab + 8), f3 = *(const float4*)(Ab + 12);
            alignas(16) unsigned short t16[16] = {
                f2b(f0.x), f2b(f0.y), f2b(f0.z), f2b(f0.w),
                f2b(f1.x), f2b(f1.y), f2b(f1.z), f2b(f1.w),
                f2b(f2.x), f2b(f2.y), f2b(f2.z), f2b(f2.w),
                f2b(f3.x), f2b(f3.y), f2b(f3.z), f2b(f3.w)};
            *(float4*)&As[ar * 32 + as0]     = ((const float4*)t16)[0];
            *(float4*)&As[ar * 32 + as0 + 8] = ((const float4*)t16)[1];
        } else {
            const unsigned short* Ab = (const unsigned short*)Av + (size_t)b * sAb;
#pragma unroll
            for (int i = 0; i < 2; i++) {
                int panel = wave * 2 + i;  // 16-row panel
                gl2lds16(&Ab[(size_t)(m0 + panel * 16 + ldr) * ldk + k0 + ldc8],
                         &As[panel * 512]);
            }
        }
#pragma unroll
        for (int i = 0; i < 2; i++) {
            int panel = wave * 2 + i;
            gl2lds16(&Bb[(size_t)(n0 + panel * 16 + ldr) * ldk + k0 + ldc8],
                     &Bs[panel * 512]);
        }
        __syncthreads();

        bf16x8 af[4], bf[4];
#pragma unroll
        for (int i = 0; i < 4; i++) {
            af[i] = *(const bf16x8*)&As[(wm * 64 + i * 16 + l16) * 32 + quad * 8];
            bf[i] = *(const bf16x8*)&Bs[(wn * 64 + i * 16 + l16) * 32 + quad * 8];
        }
#pragma unroll
        for (int mb = 0; mb < 4; mb++)
#pragma unroll
            for (int nb = 0; nb < 4; nb++)
                acc[mb][nb] = __builtin_amdgcn_mfma_f32_16x16x32_bf16(
                    af[mb], bf[nb], acc[mb][nb], 0, 0, 0);
    }

    const size_t offC = (size_t)b * sCb;
#pragma unroll
    for (int mb = 0; mb < 4; mb++)
#pragma unroll
        for (int nb = 0; nb < 4; nb++)
#pragma unroll
            for (int r = 0; r < 4; r++) {
                int row = m0 + wm * 64 + mb * 16 + quad * 4 + r;
                int col = n0 + wn * 64 + nb * 16 + l16;
                size_t idx = offC + (writeT ? (size_t)col * ldc + row
                                            : (size_t)row * ldc + col);
                if (c_f32) ((float*)Cv)[idx] = acc[mb][nb][r];
                else ((unsigned short*)Cv)[idx] = f2b(acc[mb][nb][r]);
            }
}

// ---------------------------------------------------------------------------
// 64x64 dtype-flex GEMM (round-3, verified) for small shapes.
// ---------------------------------------------------------------------------
__global__ __launch_bounds__(256) void gemm64_kernel(
    const void* __restrict__ Av, int a_f32, size_t sAb, size_t sAh,
    const unsigned short* __restrict__ B, size_t sBb, size_t sBh,
    void* __restrict__ Cv, int c_f32, int writeT, int ldc, size_t sCb, size_t sCh,
    int K, int hshift, int hmask)
{
    __shared__ unsigned short As[64][40];
    __shared__ unsigned short Bs[64][40];

    const int tid  = threadIdx.x;
    const int wave = tid >> 6, lane = tid & 63;
    const int quad = lane >> 4, l16 = lane & 15;
    const int m0 = blockIdx.x * 64, n0 = blockIdx.y * 64;
    const int bz = blockIdx.z;
    const int b = bz >> hshift, h = bz & hmask;

    f32x4 acc[4];
#pragma unroll
    for (int i = 0; i < 4; i++) acc[i] = (f32x4){0.f, 0.f, 0.f, 0.f};

    const int ldrow = tid >> 2, ldseg = (tid & 3) * 8;
    const size_t offA = (size_t)b * sAb + (size_t)h * sAh;
    const size_t offB = (size_t)b * sBb + (size_t)h * sBh;

    for (int k0 = 0; k0 < K; k0 += 32) {
        __syncthreads();
        if (a_f32) {
            const float* p = (const float*)Av + offA + (size_t)(m0 + ldrow) * K + k0 + ldseg;
            float4 lo = *(const float4*)p, hi = *(const float4*)(p + 4);
            alignas(16) unsigned short t8[8] = {
                f2b(lo.x), f2b(lo.y), f2b(lo.z), f2b(lo.w),
                f2b(hi.x), f2b(hi.y), f2b(hi.z), f2b(hi.w)};
            *(float4*)&As[ldrow][ldseg] = *(const float4*)t8;
        } else {
            const unsigned short* p = (const unsigned short*)Av + offA +
                                      (size_t)(m0 + ldrow) * K + k0 + ldseg;
            *(float4*)&As[ldrow][ldseg] = *(const float4*)p;
        }
        {
            const unsigned short* p = B + offB + (size_t)(n0 + ldrow) * K + k0 + ldseg;
            *(float4*)&Bs[ldrow][ldseg] = *(const float4*)p;
        }
        __syncthreads();

        bf16x8 a = *(const bf16x8*)&As[wave * 16 + l16][quad * 8];
#pragma unroll
        for (int nb = 0; nb < 4; nb++) {
            bf16x8 bb = *(const bf16x8*)&Bs[nb * 16 + l16][quad * 8];
            acc[nb] = __builtin_amdgcn_mfma_f32_16x16x32_bf16(a, bb, acc[nb], 0, 0, 0);
        }
    }

    const size_t offC = (size_t)b * sCb + (size_t)h * sCh;
#pragma unroll
    for (int nb = 0; nb < 4; nb++)
#pragma unroll
        for (int r = 0; r < 4; r++) {
            int row = m0 + wave * 16 + quad * 4 + r;
            int col = n0 + nb * 16 + l16;
            size_t idx = offC + (writeT ? (size_t)col * ldc + row
                                        : (size_t)row * ldc + col);
            if (c_f32) ((float*)Cv)[idx] = acc[nb][r];
            else ((unsigned short*)Cv)[idx] = f2b(acc[nb][r]);
        }
}

// ---------------------------------------------------------------------------
// WvT[h][t][e] = bf16(Wv[h][e][t])
// ---------------------------------------------------------------------------
__global__ __launch_bounds__(256) void transpose_wv_kernel(
    const float* __restrict__ Wv, unsigned short* __restrict__ WvT)
{
    int i = blockIdx.x * 256 + threadIdx.x;
    int h = i >> 15, r = i & 32767;
    int t = r >> 6, e = i & 63;
    WvT[i] = f2b(Wv[(size_t)h * 32768 + (size_t)e * 512 + t]);
}

// ---------------------------------------------------------------------------
__global__ __launch_bounds__(64) void softmax_kernel(
    const float* __restrict__ S, unsigned short* __restrict__ w)
{
    const int bh = blockIdx.x;
    const int d  = threadIdx.x;
    const float* s = S + (size_t)bh * (HD * HD) + d * HD;
    float v[64];
    float m = -1e30f;
#pragma unroll
    for (int e = 0; e < 64; e++) { v[e] = s[e] * INV_SCALE; m = fmaxf(m, v[e]); }
    float sum = 0.f;
#pragma unroll
    for (int e = 0; e < 64; e++) { v[e] = __expf(v[e] - m); sum += v[e]; }
    float rinv = 1.0f / sum;
    unsigned short* o = w + (size_t)bh * (HD * HD) + d * HD;
#pragma unroll
    for (int e = 0; e < 64; e++) o[e] = f2b(v[e] * rinv);
}

// ---------------------------------------------------------------------------
extern "C" void kernel_launch(void* const* d_in, const int* in_sizes, int n_in,
                              void* d_out, int out_size, void* d_ws, size_t ws_size,
                              hipStream_t stream)
{
    const float* q  = (const float*)d_in[0];
    const float* k  = (const float*)d_in[1];
    const float* v  = (const float*)d_in[2];
    const float* Wq = (const float*)d_in[3];
    const float* Wk = (const float*)d_in[4];
    const float* Wv = (const float*)d_in[5];
    const float* Wo = (const float*)d_in[6];

    // workspace (element counts; total 87.0 MB < 102.7 MB proven in round 2)
    unsigned short* qT   = (unsigned short*)d_ws;        // 16,777,216
    unsigned short* kT   = qT + 16777216;                // 16,777,216
    unsigned short* G    = kT + 16777216;                // 2,097,152
    unsigned short* tmpT = G + 2097152;                  // 2,097,152
    unsigned short* WkB  = tmpT + 2097152;               // 262,144
    unsigned short* WoB  = WkB + 262144;                 // 262,144
    unsigned short* WvT  = WoB + 262144;                 // 262,144
    unsigned short* w    = WvT + 262144;                 // 262,144
    unsigned short* WveT = w + 262144;                   // 2,097,152
    unsigned short* W2   = WveT + 2097152;               // 2,097,152
    float*          S    = (float*)(W2 + 2097152);       // 262,144 fp32

    // 0a. q,k -> qT,kT (bf16, [b][t][c])
    transpose_qk_kernel<<<dim3(64, 8, 16), 256, 0, stream>>>(q, k, qT, kT);
    // 0b. weight converts
    cvt_kernel<<<128, 256, 0, stream>>>(Wk, WkB, 32768);
    cvt_kernel<<<128, 256, 0, stream>>>(Wo, WoB, 32768);
    transpose_wv_kernel<<<1024, 256, 0, stream>>>(Wv, WvT);

    // 1. G[b][t][s] = sum_c qT[b][t][c] kT[b][s][c]   (K=4096)
    gemm128_kernel<<<dim3(4, 4, BS), 256, 0, stream>>>(
        qT, 0, 16777216 / 8, kT, 2097152,
        G, 0, 0, 512, 262144, 4096, 4096);

    // 2a. tmpT[b][he][t] = (G[b] * WkB^T)^T   (M=512 t, N=512 he, K=512 s)
    gemm128_kernel<<<dim3(4, 4, BS), 256, 0, stream>>>(
        G, 0, 262144, WkB, 0,
        tmpT, 0, 1, 512, 262144, 512, 512);

    // 2b. S[b,h][d][e] = Wq[h] * tmpT[b,h]^T  (M=64, N=64, K=512)
    gemm64_kernel<<<dim3(1, 1, 64), 256, 0, stream>>>(
        Wq, 1, 0, 32768, tmpT, 262144, 32768,
        S, 1, 0, 64, 32768, 4096, 512, 3, 7);

    // 3. softmax
    softmax_kernel<<<64, 64, 0, stream>>>(S, w);

    // 4. WveT[b][t][h*64+d] = (w[b,h] * WvT[h]^T)^T   (M=64, N=512, K=64)
    gemm64_kernel<<<dim3(1, 8, 64), 256, 0, stream>>>(
        w, 0, 32768, 4096, WvT, 0, 32768,
        WveT, 0, 1, 512, 262144, 64, 64, 3, 7);

    // 5. W2[b][o][t] = WoB * WveT[b]^T   (M=512, N=512, K=512)
    gemm128_kernel<<<dim3(4, 4, BS), 256, 0, stream>>>(
        WoB, 0, 0, WveT, 262144,
        W2, 0, 0, 512, 262144, 512, 512);

    // 6. out[b][c][o] = v[b] * W2[b]^T   (M=4096, N=512, K=512, A fp32)
    gemm128_kernel<<<dim3(32, 4, BS), 256, 0, stream>>>(
        v, 1, 2097152, W2, 262144,
        d_out, 1, 0, 512, 2097152, 512, 512);
}